// Round 8
// baseline (540.075 us; speedup 1.0000x reference)
//
#include <hip/hip_runtime.h>
#include <hip/hip_bf16.h>
#include <math.h>

#define Bb 4
#define Ls 1024
#define DHc 2048
#define Dh 128
#define HQc 16
#define HKc 4
#define Hc 16
#define Mrows 4096   // Bb*Ls
#define CC 64        // chunk length
#define NCH 16       // chunks per sequence

typedef __attribute__((ext_vector_type(8))) short bf16x8;
typedef __attribute__((ext_vector_type(4))) float f32x4;

__device__ inline unsigned short f2b(float f) {
    __hip_bfloat16 h = __float2bfloat16(f);
    return *(unsigned short*)&h;
}
__device__ inline float b2f(unsigned short u) {
    __hip_bfloat16 h = *(__hip_bfloat16*)&u;
    return __bfloat162float(h);
}
__device__ inline bf16x8 scale_frag(bf16x8 a, float s) {
    union { bf16x8 v; unsigned short u[8]; } x;
    x.v = a;
#pragma unroll
    for (int i = 0; i < 8; i++) x.u[i] = f2b(b2f(x.u[i]) * s);
    return x.v;
}

// async global->LDS, 16B per lane; LDS dest is wave-uniform base + lane*16
__device__ inline void load_lds16(const void* g, void* l) {
    __builtin_amdgcn_global_load_lds((const __attribute__((address_space(1))) void*)g,
                                     (__attribute__((address_space(3))) void*)l, 16, 0, 0);
}

// LDS-only barrier: orders ds ops across waves WITHOUT draining vmcnt(0).
__device__ inline void bar_lds() {
    asm volatile("s_waitcnt lgkmcnt(0)" ::: "memory");
    __builtin_amdgcn_s_barrier();
    asm volatile("" ::: "memory");
}

// ---------------------------------------------------------------------------
// fp32 -> bf16 elementwise convert (n % 4 == 0)
// ---------------------------------------------------------------------------
__global__ void f32_to_bf16(const float* __restrict__ in, __hip_bfloat16* __restrict__ out, int n)
{
    int i = (blockIdx.x * 256 + threadIdx.x) * 4;
    if (i >= n) return;
    float4 v = *(const float4*)(in + i);
    __hip_bfloat16 h[4];
    h[0] = __float2bfloat16(v.x); h[1] = __float2bfloat16(v.y);
    h[2] = __float2bfloat16(v.z); h[3] = __float2bfloat16(v.w);
    *(uint2*)(out + i) = *(uint2*)h;
}

// ---------------------------------------------------------------------------
// Transpose + convert: W fp32 [Krows, Ncols] -> BT bf16 [Ncols, Krows].
// ---------------------------------------------------------------------------
__launch_bounds__(256)
__global__ void transpose_to_bf16(const float* __restrict__ W, __hip_bfloat16* __restrict__ BT,
                                  int Krows, int Ncols)
{
    __shared__ float tile[64][65];
    const int n0 = blockIdx.x * 64, k0 = blockIdx.y * 64;
    const int tx = threadIdx.x & 63, ty = threadIdx.x >> 6;
#pragma unroll
    for (int r = ty; r < 64; r += 4)
        tile[r][tx] = W[(size_t)(k0 + r) * Ncols + n0 + tx];
    __syncthreads();
#pragma unroll
    for (int r = ty; r < 64; r += 4)
        BT[(size_t)(n0 + r) * Krows + k0 + tx] = __float2bfloat16(tile[tx][r]);
}

// ---------------------------------------------------------------------------
// bf16 MFMA GEMM: C[M,N] = A[M,K] @ BT[N,K]^T. 128x128 tile, BK=32.
// m97 structure + slot-XOR LDS swizzle: rows at 64B stride made all b128
// frag reads an 8-WAY bank conflict (bank = 16(row&1)+4slot+pass; 10.5M
// SQ_LDS_BANK_CONFLICT cycles/dispatch — the critical path). Fix per rule
// #21 (both-sides-or-neither, global_load_lds writes linearly): pre-swizzle
// the GLOBAL source column (kk = ((l&3)^((l>>3)&3))*8) and swizzle the READ
// slot (fs = ((lane>>4)^((fr>>1)&3))*8). Quarter-wave now touches 8 bank
// groups x 2 lanes = 2-way = free (m136).
// ---------------------------------------------------------------------------
__launch_bounds__(256)
__global__ void gemm_bt_bf16(const __hip_bfloat16* __restrict__ A, const __hip_bfloat16* __restrict__ BT,
                             void* __restrict__ C, int N, int K, int c_bf16)
{
    __shared__ __align__(16) unsigned short As[128 * 32];
    __shared__ __align__(16) unsigned short Bs[128 * 32];
    const int tid = threadIdx.x;
    const int lane = tid & 63;
    const int wave = tid >> 6;
    const int wm = (wave >> 1) * 64, wn = (wave & 1) * 64;
    const int row0 = blockIdx.y * 128, col0 = blockIdx.x * 128;

    const int r0 = (wave * 2 + 0) * 16 + (lane >> 2);
    const int r1 = (wave * 2 + 1) * 16 + (lane >> 2);
    const int kk = ((lane & 3) ^ ((lane >> 3) & 3)) * 8;   // swizzled source slot
    const __hip_bfloat16* Ap0 = A + (size_t)(row0 + r0) * K + kk;
    const __hip_bfloat16* Ap1 = A + (size_t)(row0 + r1) * K + kk;
    const __hip_bfloat16* Bp0 = BT + (size_t)(col0 + r0) * K + kk;
    const __hip_bfloat16* Bp1 = BT + (size_t)(col0 + r1) * K + kk;
    unsigned short* sa0 = &As[(wave * 2 + 0) * 16 * 32];  // wave-uniform dests (linear)
    unsigned short* sa1 = &As[(wave * 2 + 1) * 16 * 32];
    unsigned short* sb0 = &Bs[(wave * 2 + 0) * 16 * 32];
    unsigned short* sb1 = &Bs[(wave * 2 + 1) * 16 * 32];

    f32x4 acc[4][4];
#pragma unroll
    for (int i = 0; i < 4; i++)
#pragma unroll
        for (int j = 0; j < 4; j++) acc[i][j] = (f32x4){0.f, 0.f, 0.f, 0.f};

    const int fr = lane & 15;
    const int fs = (((lane >> 4) ^ ((fr >> 1) & 3))) * 8;  // swizzled read slot

    for (int k0 = 0; k0 < K; k0 += 32) {
        __syncthreads();                 // prev tile readers done
        load_lds16(Ap0, sa0);
        load_lds16(Ap1, sa1);
        load_lds16(Bp0, sb0);
        load_lds16(Bp1, sb1);
        Ap0 += 32; Ap1 += 32; Bp0 += 32; Bp1 += 32;
        __syncthreads();                 // drains vmcnt(0): staged data visible

        bf16x8 af[4], bfr[4];
#pragma unroll
        for (int i = 0; i < 4; i++)
            af[i] = *(const bf16x8*)&As[(wm + i * 16 + fr) * 32 + fs];
#pragma unroll
        for (int j = 0; j < 4; j++)
            bfr[j] = *(const bf16x8*)&Bs[(wn + j * 16 + fr) * 32 + fs];
#pragma unroll
        for (int i = 0; i < 4; i++)
#pragma unroll
            for (int j = 0; j < 4; j++)
                acc[i][j] = __builtin_amdgcn_mfma_f32_16x16x32_bf16(af[i], bfr[j], acc[i][j], 0, 0, 0);
    }

    const int cr = (lane >> 4) * 4;
    const int cc = lane & 15;
#pragma unroll
    for (int i = 0; i < 4; i++)
#pragma unroll
        for (int j = 0; j < 4; j++) {
            size_t base = (size_t)(row0 + wm + i * 16 + cr) * N + (col0 + wn + j * 16 + cc);
#pragma unroll
            for (int p = 0; p < 4; p++) {
                if (c_bf16)
                    ((__hip_bfloat16*)C)[base + (size_t)p * N] = __float2bfloat16(acc[i][j][p]);
                else
                    ((float*)C)[base + (size_t)p * N] = acc[i][j][p];
            }
        }
}

// ---------------------------------------------------------------------------
// Fused projection GEMM: [4096,2048] @ BTall[5120,2048]^T, C routed per
// col-block: cols 0-2047 -> preQ, 2048-2559 -> preK, 2560-3071 -> preV,
// 3072-5119 -> gate. Grid 40x32 = 1280 blocks. Same slot-XOR LDS swizzle
// as gemm_bt_bf16 (see comment there).
// ---------------------------------------------------------------------------
__launch_bounds__(256)
__global__ void gemm_proj_fused(const __hip_bfloat16* __restrict__ A, const __hip_bfloat16* __restrict__ BT,
                                __hip_bfloat16* __restrict__ preQ, __hip_bfloat16* __restrict__ preK,
                                __hip_bfloat16* __restrict__ preV, __hip_bfloat16* __restrict__ gate)
{
    const int K = 2048;
    __shared__ __align__(16) unsigned short As[128 * 32];
    __shared__ __align__(16) unsigned short Bs[128 * 32];
    const int tid = threadIdx.x;
    const int lane = tid & 63;
    const int wave = tid >> 6;
    const int wm = (wave >> 1) * 64, wn = (wave & 1) * 64;
    const int row0 = blockIdx.y * 128;
    const int cb = blockIdx.x;           // 0..39
    const int col0 = cb * 128;           // BTall row base

    // C routing (uniform per block)
    __hip_bfloat16* Cb; int Nloc, c0loc;
    if (cb < 16)      { Cb = preQ; Nloc = 2048; c0loc = cb * 128; }
    else if (cb < 20) { Cb = preK; Nloc = 512;  c0loc = (cb - 16) * 128; }
    else if (cb < 24) { Cb = preV; Nloc = 512;  c0loc = (cb - 20) * 128; }
    else              { Cb = gate; Nloc = 2048; c0loc = (cb - 24) * 128; }

    const int r0 = (wave * 2 + 0) * 16 + (lane >> 2);
    const int r1 = (wave * 2 + 1) * 16 + (lane >> 2);
    const int kk = ((lane & 3) ^ ((lane >> 3) & 3)) * 8;   // swizzled source slot
    const __hip_bfloat16* Ap0 = A + (size_t)(row0 + r0) * K + kk;
    const __hip_bfloat16* Ap1 = A + (size_t)(row0 + r1) * K + kk;
    const __hip_bfloat16* Bp0 = BT + (size_t)(col0 + r0) * K + kk;
    const __hip_bfloat16* Bp1 = BT + (size_t)(col0 + r1) * K + kk;
    unsigned short* sa0 = &As[(wave * 2 + 0) * 16 * 32];
    unsigned short* sa1 = &As[(wave * 2 + 1) * 16 * 32];
    unsigned short* sb0 = &Bs[(wave * 2 + 0) * 16 * 32];
    unsigned short* sb1 = &Bs[(wave * 2 + 1) * 16 * 32];

    f32x4 acc[4][4];
#pragma unroll
    for (int i = 0; i < 4; i++)
#pragma unroll
        for (int j = 0; j < 4; j++) acc[i][j] = (f32x4){0.f, 0.f, 0.f, 0.f};

    const int fr = lane & 15;
    const int fs = (((lane >> 4) ^ ((fr >> 1) & 3))) * 8;  // swizzled read slot

    for (int k0 = 0; k0 < K; k0 += 32) {
        __syncthreads();
        load_lds16(Ap0, sa0);
        load_lds16(Ap1, sa1);
        load_lds16(Bp0, sb0);
        load_lds16(Bp1, sb1);
        Ap0 += 32; Ap1 += 32; Bp0 += 32; Bp1 += 32;
        __syncthreads();

        bf16x8 af[4], bfr[4];
#pragma unroll
        for (int i = 0; i < 4; i++)
            af[i] = *(const bf16x8*)&As[(wm + i * 16 + fr) * 32 + fs];
#pragma unroll
        for (int j = 0; j < 4; j++)
            bfr[j] = *(const bf16x8*)&Bs[(wn + j * 16 + fr) * 32 + fs];
#pragma unroll
        for (int i = 0; i < 4; i++)
#pragma unroll
            for (int j = 0; j < 4; j++)
                acc[i][j] = __builtin_amdgcn_mfma_f32_16x16x32_bf16(af[i], bfr[j], acc[i][j], 0, 0, 0);
    }

    const int cr = (lane >> 4) * 4;
    const int cc = lane & 15;
#pragma unroll
    for (int i = 0; i < 4; i++)
#pragma unroll
        for (int j = 0; j < 4; j++) {
            size_t base = (size_t)(row0 + wm + i * 16 + cr) * Nloc + (c0loc + wn + j * 16 + cc);
#pragma unroll
            for (int p = 0; p < 4; p++)
                Cb[base + (size_t)p * Nloc] = __float2bfloat16(acc[i][j][p]);
        }
}

// ---------------------------------------------------------------------------
// Causal depthwise conv (K=4) + SiLU + optional l2norm(+scale). bf16 in/out.
// ---------------------------------------------------------------------------
__global__ void conv_silu_norm(const __hip_bfloat16* __restrict__ pre, const float* __restrict__ w,
                               __hip_bfloat16* __restrict__ out, int NH, int do_norm, float scale)
{
    __shared__ float red[2];
    const int idx = blockIdx.x;
    const int head = idx % NH;
    const int l = (idx / NH) % Ls;
    const int b = idx / (NH * Ls);
    const int C = NH * Dh;
    const int c = head * Dh + threadIdx.x;
    const __hip_bfloat16* base = pre + ((size_t)b * Ls + l) * C + c;
    const float4 wv = *(const float4*)(w + (size_t)c * 4);

    float v0 = (l >= 3) ? __bfloat162float(base[-3 * C]) : 0.f;
    float v1 = (l >= 2) ? __bfloat162float(base[-2 * C]) : 0.f;
    float v2 = (l >= 1) ? __bfloat162float(base[-1 * C]) : 0.f;
    float v3 = __bfloat162float(base[0]);
    float y = v0 * wv.x + v1 * wv.y + v2 * wv.z + v3 * wv.w;
    y = y / (1.f + expf(-y));   // SiLU

    if (do_norm) {
        float ss = y * y;
#pragma unroll
        for (int off = 32; off > 0; off >>= 1) ss += __shfl_xor(ss, off);
        if ((threadIdx.x & 63) == 0) red[threadIdx.x >> 6] = ss;
        __syncthreads();
        float tot = red[0] + red[1];
        y = y * rsqrtf(tot + 1e-6f) * scale;
    }
    out[((size_t)b * Ls + l) * C + c] = __float2bfloat16(y);
}

// ---------------------------------------------------------------------------
// Pack Wb,Wgk fp32 [2048][16] -> WT32 bf16 [32][2048] (rows 0-15 Wb^T, 16-31 Wgk^T)
// ---------------------------------------------------------------------------
__global__ void pack_wt32(const float* __restrict__ Wb, const float* __restrict__ Wgk,
                          __hip_bfloat16* __restrict__ WT)
{
    const int t = blockIdx.x * 64 + (threadIdx.x & 63);
    const int h0 = (threadIdx.x >> 6) * 4;
#pragma unroll
    for (int i = 0; i < 4; i++) {
        const int h = h0 + i;
        WT[(size_t)h * 2048 + t]        = __float2bfloat16(Wb[(size_t)t * 16 + h]);
        WT[(size_t)(16 + h) * 2048 + t] = __float2bfloat16(Wgk[(size_t)t * 16 + h]);
    }
}

// ---------------------------------------------------------------------------
// beta/g via MFMA skinny GEMM over xbf: [4096,2048]@[2048,32].
// ---------------------------------------------------------------------------
__launch_bounds__(256)
__global__ void proj_bg(const __hip_bfloat16* __restrict__ xbf, const __hip_bfloat16* __restrict__ WT32,
                        const float* __restrict__ A_log, const float* __restrict__ dt_bias,
                        float* __restrict__ beta, float* __restrict__ g)
{
    const int tid = threadIdx.x;
    const int lane = tid & 63;
    const int wave = tid >> 6;
    const int q = lane >> 4;     // 0..3 (k-subgroup)
    const int cL = lane & 15;    // 0..15 (A-row / B-col within frag)
    const int row0 = blockIdx.x * 64 + wave * 16;

    const unsigned short* xu = (const unsigned short*)xbf;
    const unsigned short* wu = (const unsigned short*)WT32;

    f32x4 accB = (f32x4){0.f, 0.f, 0.f, 0.f};
    f32x4 accG = (f32x4){0.f, 0.f, 0.f, 0.f};
    const size_t arow = (size_t)(row0 + cL) * 2048;
    const size_t brow = (size_t)cL * 2048;         // Wb^T head cL
    const size_t grow = (size_t)(16 + cL) * 2048;  // Wgk^T head cL

#pragma unroll 4
    for (int k = 0; k < 2048; k += 32) {
        bf16x8 af  = *(const bf16x8*)&xu[arow + k + q * 8];
        bf16x8 wbf = *(const bf16x8*)&wu[brow + k + q * 8];
        bf16x8 wgf = *(const bf16x8*)&wu[grow + k + q * 8];
        accB = __builtin_amdgcn_mfma_f32_16x16x32_bf16(af, wbf, accB, 0, 0, 0);
        accG = __builtin_amdgcn_mfma_f32_16x16x32_bf16(af, wgf, accG, 0, 0, 0);
    }

    // C layout: row = 4q+p (block-local), col = cL (head)
    const float al = __expf(A_log[cL]);
    const float db = dt_bias[cL];
#pragma unroll
    for (int p = 0; p < 4; p++) {
        const int r = row0 + 4 * q + p;
        beta[(size_t)r * 16 + cL] = 1.f / (1.f + __expf(-accB[p]));
        float z = accG[p] + db;
        float sp = (z > 20.f) ? z : log1pf(__expf(z));
        g[(size_t)r * 16 + cL] = -al * sp;
    }
}

// ---------------------------------------------------------------------------
// Per-chunk inclusive prefix sum of log-decay g. grid = BH*NCH blocks, 64 thr.
// ---------------------------------------------------------------------------
__global__ void bcum_kernel(const float* __restrict__ g, float* __restrict__ bcum)
{
    const int c = blockIdx.x & 15;
    const int bh = blockIdx.x >> 4;
    const int b = bh >> 4;
    const int h = bh & 15;
    const int t = threadIdx.x;
    float v = g[((size_t)(b * Ls + c * CC + t)) * 16 + h];
#pragma unroll
    for (int d = 1; d < 64; d <<= 1) {
        float n = __shfl_up(v, d, 64);
        if (t >= d) v += n;
    }
    bcum[(size_t)blockIdx.x * 64 + t] = v;
}

// ---------------------------------------------------------------------------
// Phase 1 (parallel over 1024 (b,h,chunk) tasks):
//   P = K K^T (MFMA); A[t][s] = beta_t exp(bc_t-bc_s) P (s<t);
//   forward-substitute (I+A)[U|Z] = [diag(beta)V | diag(beta)diag(exp(bc))K]
// U stored TRANSPOSED ([v][t], stride 64) == layout phase 2 overwrites with
// W^T (race fix: phase-2 v-slice blocks stay in disjoint slab ranges).
// Z is written to the DEAD xbf slot (gate occupies the Zb slot).
// ---------------------------------------------------------------------------
__launch_bounds__(256)
__global__ void gdn_phase1(const __hip_bfloat16* __restrict__ kc, const __hip_bfloat16* __restrict__ vc,
                           const float* __restrict__ bb, const float* __restrict__ bcum,
                           __hip_bfloat16* __restrict__ U, __hip_bfloat16* __restrict__ Z)
{
    const int task = blockIdx.x;
    const int c = task & 15;
    const int bh = task >> 4;
    const int b = bh >> 4;
    const int h = bh & 15;
    const int hk = h >> 2;
    const int tid = threadIdx.x;
    const int lane = tid & 63;
    const int wave = tid >> 6;
    const int q = lane >> 4;
    const int cL = lane & 15;

    __shared__ float Ab[64][68];
    __shared__ float sbeta[64], sbc[64];

    if (tid < 64) {
        sbeta[tid] = bb[((size_t)(b * Ls + c * CC + tid)) * 16 + h];
        sbc[tid] = bcum[((size_t)bh * 16 + c) * 64 + tid];
    }
    __syncthreads();

    const unsigned short* ku = (const unsigned short*)kc;
    const unsigned short* vu = (const unsigned short*)vc;

    // P = K K^T : wave w owns rows t in [16w,16w+16)
    f32x4 pacc[4];
#pragma unroll
    for (int j = 0; j < 4; j++) pacc[j] = (f32x4){0.f, 0.f, 0.f, 0.f};
    {
        const int t = 16 * wave + cL;
        const size_t krow = (((size_t)(b * Ls + c * CC + t)) * 4 + hk) * 128;
#pragma unroll
        for (int ks = 0; ks < 4; ks++) {
            bf16x8 af = *(const bf16x8*)&ku[krow + ks * 32 + q * 8];
#pragma unroll
            for (int j = 0; j < 4; j++) {
                const int s = 16 * j + cL;
                bf16x8 bf = *(const bf16x8*)&ku[(((size_t)(b * Ls + c * CC + s)) * 4 + hk) * 128 + ks * 32 + q * 8];
                pacc[j] = __builtin_amdgcn_mfma_f32_16x16x32_bf16(af, bf, pacc[j], 0, 0, 0);
            }
        }
    }
    // dump A (fp32, zero on/above diagonal)
#pragma unroll
    for (int j = 0; j < 4; j++)
#pragma unroll
        for (int p = 0; p < 4; p++) {
            const int t = 16 * wave + 4 * q + p;
            const int s = 16 * j + cL;
            float val = 0.f;
            if (s < t) val = sbeta[t] * __expf(sbc[t] - sbc[s]) * pacc[j][p];
            Ab[t][s] = val;
        }
    __syncthreads();

    // forward substitution, thread = one column of [U | Z]
    float u[64];
    const int j = tid;
    if (j < 128) {
#pragma unroll
        for (int t = 0; t < 64; t++)
            u[t] = sbeta[t] * b2f(vu[(((size_t)(b * Ls + c * CC + t)) * 4 + hk) * 128 + j]);
    } else {
        const int k = j - 128;
#pragma unroll
        for (int t = 0; t < 64; t++)
            u[t] = sbeta[t] * __expf(sbc[t]) * b2f(ku[(((size_t)(b * Ls + c * CC + t)) * 4 + hk) * 128 + k]);
    }
#pragma unroll
    for (int t = 1; t < 64; t++) {
        const float4* ar = (const float4*)Ab[t];
        const int nf = (t + 3) >> 2;
        float a0 = 0.f, a1 = 0.f, a2 = 0.f, a3 = 0.f;
#pragma unroll
        for (int i = 0; i < nf; i++) {
            float4 av = ar[i];
            a0 = fmaf(av.x, u[4 * i + 0], a0);
            a1 = fmaf(av.y, u[4 * i + 1], a1);
            a2 = fmaf(av.z, u[4 * i + 2], a2);
            a3 = fmaf(av.w, u[4 * i + 3], a3);
        }
        u[t] -= (a0 + a1) + (a2 + a3);
    }
    const size_t slab = ((size_t)bh * 16 + c) * 8192;
    if (j < 128) {
        // U^T store: thread j owns v-column j -> contiguous 64 ushorts = 8x16B
        unsigned short* Up = (unsigned short*)U + slab + (size_t)j * 64;
#pragma unroll
        for (int t8 = 0; t8 < 8; t8++) {
            union { bf16x8 v; unsigned short us[8]; } pk;
#pragma unroll
            for (int e = 0; e < 8; e++) pk.us[e] = f2b(u[8 * t8 + e]);
            *(bf16x8*)&Up[t8 * 8] = pk.v;
        }
    } else {
#pragma unroll
        for (int t = 0; t < 64; t++) Z[slab + t * 128 + (j - 128)] = __float2bfloat16(u[t]);
    }
}

// ---------------------------------------------------------------------------
// Phase 2 v4: sequential over 16 chunks; 256 blocks = (b,h) x 4 v-QUARTERS.
// Block owns 32 v-columns of state T[v][k]:
//   per chunk: W = U - Z T^T ; O1 = Q T^T (row-scaled exp(bc_t) in epilogue)
//   ; T = eC T + W^T K_hat
// Barriers are lgkmcnt-only (LDS deps); global deps register-carried.
// Each quarter touches only its [vbase*64, vbase*64+2048) slab range for
// both the U^T read and the W^T write -> race-free vs sibling blocks.
// ---------------------------------------------------------------------------
__launch_bounds__(256, 1)
__global__ void gdn_phase2(const __hip_bfloat16* __restrict__ qc, const __hip_bfloat16* __restrict__ kc,
                           __hip_bfloat16* Uw /* in: U^T, out: W^T (aliased) */,
                           const __hip_bfloat16* __restrict__ Zbuf,
                           const float* __restrict__ bcum, float* __restrict__ Obuf)
{
    const int blk = blockIdx.x;
    const int quarter = blk & 3;
    const int bh = blk >> 2;
    const int b = bh >> 4;
    const int h = bh & 15;
    const int hk = h >> 2;
    const int vbase = quarter * 32;
    const int tid = threadIdx.x;
    const int lane = tid & 63;
    const int wave = tid >> 6;
    const int q = lane >> 4;
    const int cL = lane & 15;

    // LDS tiles
    __shared__ __align__(16) unsigned short Tb[32 * 136]; // T as B-frag: [vloc][k]
    __shared__ __align__(16) unsigned short Kt[128 * 72]; // K_hat^T: [k][tloc]
    __shared__ __align__(16) unsigned short Wt[32 * 72];  // W^T: [vloc][t]
    __shared__ __align__(16) unsigned short Us[32 * 72];  // U^T: [vloc][t]

    const unsigned short* qu = (const unsigned short*)qc;
    const unsigned short* ku = (const unsigned short*)kc;
    unsigned short* Uu = (unsigned short*)Uw;
    const unsigned short* Zu = (const unsigned short*)Zbuf;

    const int tloc = tid & 63;          // staging row (t for K, etc.)
    const int kg = tid >> 6;            // k-group for K staging
    const int trow = 16 * wave + cL;    // A-frag row (chunk-local t) for G1/G2
    const int wv = (wave & 1) * 16;     // wave's v-row base within quarter (G3)
    const int wk = (wave >> 1) * 4;     // wave's k-tile base (G3), tiles of 16

    // state accumulators: wave owns v in [wv,wv+16), k in [64*(wave>>1),+64)
    f32x4 Tacc[4];
#pragma unroll
    for (int j = 0; j < 4; j++) Tacc[j] = (f32x4){0.f, 0.f, 0.f, 0.f};

    // ---- prefetch registers (chunk c+1 loaded during chunk c) ----
    bf16x8 Kreg[4], Zreg[4], Qreg[4];
    uint4 Ureg;
    float p_bctl, p_bc63;
    float4 p_bct4;

    auto prefetch = [&](int c) {
        const size_t base_t = (size_t)b * Ls + (size_t)c * CC;
        const size_t slab = ((size_t)bh * 16 + c) * 8192;
        const size_t krow = ((base_t + tloc) * 4 + hk) * 128 + 32 * kg;
#pragma unroll
        for (int m = 0; m < 4; m++) Kreg[m] = *(const bf16x8*)&ku[krow + m * 8];
        // U^T quarter: row v = vbase + (tid>>3), cols t = (tid&7)*8 .. +7
        Ureg = *(const uint4*)&Uu[slab + (size_t)(vbase + (tid >> 3)) * 64 + (tid & 7) * 8];
        const size_t zrow = slab + (size_t)trow * 128;
        const size_t qrow = ((base_t + trow) * 16 + h) * 128;
#pragma unroll
        for (int ks = 0; ks < 4; ks++) {
            Zreg[ks] = *(const bf16x8*)&Zu[zrow + ks * 32 + q * 8];
            Qreg[ks] = *(const bf16x8*)&qu[qrow + ks * 32 + q * 8];
        }
        const float* bc = bcum + ((size_t)bh * 16 + c) * 64;
        p_bctl = bc[tloc];
        p_bc63 = bc[63];
        p_bct4 = *(const float4*)&bc[16 * wave + 4 * q];  // bc at t=16w+4q+p
    };

    prefetch(0);

    for (int c = 0; c < NCH; ++c) {
        // consume prefetched values into locals
        bf16x8 kr[4], zr[4], qr[4];
        uint4 ur;
#pragma unroll
        for (int m = 0; m < 4; m++) { kr[m] = Kreg[m]; zr[m] = Zreg[m]; qr[m] = Qreg[m]; }
        ur = Ureg;
        const float bctl = p_bctl, bc63 = p_bc63;
        const float4 bct4 = p_bct4;
        const size_t slab = ((size_t)bh * 16 + c) * 8192;

        // issue next chunk's global loads now (land during this chunk's compute)
        if (c + 1 < NCH) prefetch(c + 1);

        const float ek = __expf(bc63 - bctl);   // K_hat row scale (my tloc)
        const float eC = __expf(bc63);          // full-chunk decay

        bar_lds();  // barrier 1: prev chunk readers of Tb/Kt/Us/Wt done

        // stage K_hat^T: rows k=32kg+8m+e, col tloc
#pragma unroll
        for (int m = 0; m < 4; m++) {
            union { bf16x8 v; unsigned short us[8]; } kv;
            kv.v = scale_frag(kr[m], ek);
#pragma unroll
            for (int e = 0; e < 8; e++) Kt[(32 * kg + 8 * m + e) * 72 + tloc] = kv.us[e];
        }
        // stage U^T quarter: [vloc][t]
        *(uint4*)&Us[(tid >> 3) * 72 + (tid & 7) * 8] = ur;
        // dump T into Tb: row v=wv+4q+p, col k=64*(wave>>1)+16j+cL
#pragma unroll
        for (int j = 0; j < 4; j++)
#pragma unroll
            for (int p = 0; p < 4; p++)
                Tb[(wv + 4 * q + p) * 136 + (wave >> 1) * 64 + 16 * j + cL] = f2b(Tacc[j][p]);

        bar_lds();  // barrier 2: staging visible

        // G1: W' = Z T^T ; G2: O1 = Q T^T   (output [t][v], 16x16 tiles)
        f32x4 Wacc[2], Oacc[2];
#pragma unroll
        for (int j = 0; j < 2; j++) { Wacc[j] = (f32x4){0.f,0.f,0.f,0.f}; Oacc[j] = (f32x4){0.f,0.f,0.f,0.f}; }
#pragma unroll
        for (int ks = 0; ks < 4; ks++) {
#pragma unroll
            for (int j = 0; j < 2; j++) {
                bf16x8 bt = *(const bf16x8*)&Tb[(16 * j + cL) * 136 + 32 * ks + 8 * q];
                Wacc[j] = __builtin_amdgcn_mfma_f32_16x16x32_bf16(zr[ks], bt, Wacc[j], 0, 0, 0);
                Oacc[j] = __builtin_amdgcn_mfma_f32_16x16x32_bf16(qr[ks], bt, Oacc[j], 0, 0, 0);
            }
        }
        // epilogue: W = U - W'; dump W^T; store O1*exp(bc_t) (fp32 row scale)
        float e4[4] = {__expf(bct4.x), __expf(bct4.y), __expf(bct4.z), __expf(bct4.w)};
#pragma unroll
        for (int j = 0; j < 2; j++)
#pragma unroll
            for (int p = 0; p < 4; p++) {
                const int t = 16 * wave + 4 * q + p;
                const int v = 16 * j + cL;
                const float w = b2f(Us[v * 72 + t]) - Wacc[j][p];
                Wt[v * 72 + t] = f2b(w);
                Obuf[((size_t)b * Ls + c * CC + t) * 2048 + h * 128 + vbase + v] = Oacc[j][p] * e4[p];
            }

        bar_lds();  // barrier 3: Wt complete

        // store W^T to global over U slab (phase 3 layout: [vglobal][t], stride 64)
        {
            const int vloc = tid >> 3, part = tid & 7;
            const size_t dst = slab + (size_t)(vbase + vloc) * 64 + part * 8;
            *(uint4*)&Uu[dst] = *(const uint4*)&Wt[vloc * 72 + part * 8];
        }
        // G3: T = eC*T + W^T K_hat  (output [v][k]; wave's 16v x 64k region)
#pragma unroll
        for (int j = 0; j < 4; j++)
#pragma unroll
            for (int p = 0; p < 4; p++) Tacc[j][p] *= eC;
#pragma unroll
        for (int ks = 0; ks < 2; ks++) {
            bf16x8 aw = *(const bf16x8*)&Wt[(wv + cL) * 72 + 32 * ks + 8 * q];
#pragma unroll
            for (int j = 0; j < 4; j++) {
                bf16x8 bk = *(const bf16x8*)&Kt[((wk + j) * 16 + cL) * 72 + 32 * ks + 8 * q];
                Tacc[j] = __builtin_amdgcn_mfma_f32_16x16x32_bf16(aw, bk, Tacc[j], 0, 0, 0);
            }
        }
    }
}

// ---------------------------------------------------------------------------
// Phase 3 (parallel over 1024 (b,h,chunk) tasks):
//   M[t][s] = exp(bc_t-bc_s) (q_t.k_s), s<=t;  O += M W  (W^T read from Uw)
// ---------------------------------------------------------------------------
__launch_bounds__(256)
__global__ void gdn_phase3(const __hip_bfloat16* __restrict__ qc, const __hip_bfloat16* __restrict__ kc,
                           const __hip_bfloat16* __restrict__ WT, const float* __restrict__ bcum,
                           float* __restrict__ Obuf)
{
    const int task = blockIdx.x;
    const int c = task & 15;
    const int bh = task >> 4;
    const int b = bh >> 4;
    const int h = bh & 15;
    const int hk = h >> 2;
    const int tid = threadIdx.x;
    const int lane = tid & 63;
    const int wave = tid >> 6;
    const int q = lane >> 4;
    const int cL = lane & 15;

    __shared__ __align__(16) unsigned short Mb[64 * 72];
    __shared__ float sbc[64];

    if (tid < 64) sbc[tid] = bcum[((size_t)bh * 16 + c) * 64 + tid];
    __syncthreads();

    const unsigned short* qu = (const unsigned short*)qc;
    const unsigned short* ku = (const unsigned short*)kc;
    const unsigned short* wu = (const unsigned short*)WT;

    // Pq = Q K^T
    f32x4 pacc[4];
#pragma unroll
    for (int j = 0; j < 4; j++) pacc[j] = (f32x4){0.f, 0.f, 0.f, 0.f};
    {
        const int t = 16 * wave + cL;
        const size_t qrow = (((size_t)(b * Ls + c * CC + t)) * 16 + h) * 128;
#pragma unroll
        for (int ks = 0; ks < 4; ks++) {
            bf16x8 aq = *(const bf16x8*)&qu[qrow + ks * 32 + q * 8];
#pragma unroll
            for (int j = 0; j < 4; j++) {
                const int s = 16 * j + cL;
                bf16x8 bk = *(const bf16x8*)&ku[(((size_t)(b * Ls + c * CC + s)) * 4 + hk) * 128 + ks * 32 + q * 8];
                pacc[j] = __builtin_amdgcn_mfma_f32_16x16x32_bf16(aq, bk, pacc[j], 0, 0, 0);
            }
        }
    }
#pragma unroll
    for (int j = 0; j < 4; j++)
#pragma unroll
        for (int p = 0; p < 4; p++) {
            const int t = 16 * wave + 4 * q + p;
            const int s = 16 * j + cL;
            const float val = (s <= t) ? __expf(sbc[t] - sbc[s]) * pacc[j][p] : 0.f;
            Mb[t * 72 + s] = f2b(val);
        }
    __syncthreads();

    // O2 = M W ; B-frags from W^T (global, contiguous)
    f32x4 oacc[8];
#pragma unroll
    for (int j = 0; j < 8; j++) oacc[j] = (f32x4){0.f, 0.f, 0.f, 0.f};
    const size_t slab = ((size_t)bh * 16 + c) * 8192;
#pragma unroll
    for (int ks = 0; ks < 2; ks++) {
        bf16x8 am = *(const bf16x8*)&Mb[(16 * wave + cL) * 72 + ks * 32 + q * 8];
#pragma unroll
        for (int j = 0; j < 8; j++) {
            const int v = 16 * j + cL;
            bf16x8 bw = *(const bf16x8*)&wu[slab + (size_t)v * 64 + ks * 32 + q * 8];
            oacc[j] = __builtin_amdgcn_mfma_f32_16x16x32_bf16(am, bw, oacc[j], 0, 0, 0);
        }
    }
#pragma unroll
    for (int j = 0; j < 8; j++)
#pragma unroll
        for (int p = 0; p < 4; p++) {
            const int t = 16 * wave + 4 * q + p;
            const int v = 16 * j + cL;
            const size_t a = ((size_t)(b * Ls + c * CC + t)) * 2048 + h * 128 + v;
            Obuf[a] += oacc[j][p];
        }
}

// ---------------------------------------------------------------------------
// FusedRMSNormGated: reads fp32 o, bf16 gate; writes bf16 normalized o.
// ---------------------------------------------------------------------------
__global__ void gated_rmsnorm(const float* __restrict__ o, const __hip_bfloat16* __restrict__ gate,
                              const float* __restrict__ w, __hip_bfloat16* __restrict__ out)
{
    const size_t row = blockIdx.x;
    const float* op = o + row * Dh;
    const __hip_bfloat16* gp = gate + row * Dh;
    const int t = threadIdx.x;
    float o0 = op[t], o1 = op[t + 64];
    float ss = o0 * o0 + o1 * o1;
#pragma unroll
    for (int off = 32; off > 0; off >>= 1) ss += __shfl_xor(ss, off);
    float r = rsqrtf(ss * (1.f / 128.f) + 1e-5f);
    float g0 = __bfloat162float(gp[t]), g1 = __bfloat162float(gp[t + 64]);
    out[row * Dh + t]      = __float2bfloat16(o0 * r * w[t]      * (g0 / (1.f + expf(-g0))));
    out[row * Dh + t + 64] = __float2bfloat16(o1 * r * w[t + 64] * (g1 / (1.f + expf(-g1))));
}

// ---------------------------------------------------------------------------
extern "C" void kernel_launch(void* const* d_in, const int* in_sizes, int n_in,
                              void* d_out, int out_size, void* d_ws, size_t ws_size,
                              hipStream_t stream)
{
    const float* x     = (const float*)d_in[0];
    const float* Wq    = (const float*)d_in[1];
    const float* Wk    = (const float*)d_in[2];
    const float* Wv    = (const float*)d_in[3];
    const float* Wb    = (const float*)d_in[4];
    const float* Wgk   = (const float*)d_in[5];
    const float* A_log = (const float*)d_in[6];
    const float* dtb   = (const float*)d_in[7];
    const float* cq    = (const float*)d_in[8];
    const float* ck    = (const float*)d_in[9];
    const float* cv    = (const float*)d_in[10];
    const float* Wg    = (const float*)d_in[11];
    const float* onw   = (const float*)d_in[12];
    const float* Wo    = (const float*)d_in[13];

    // --- workspace layout (bytes), total 75,759,616 B ---
    char* wsb = (char*)d_ws;
    __hip_bfloat16* xbf  = (__hip_bfloat16*)(wsb + 0);          // [4096,2048] 16.78 MB; DEAD after
                                                                // gemm_proj_fused -> reused as Z
    __hip_bfloat16* qcb  = (__hip_bfloat16*)(wsb + 16777216);   // [4096,16,128] 16.78 MB
    __hip_bfloat16* kcb  = (__hip_bfloat16*)(wsb + 33554432);   // [4096,4,128]   4.19 MB
    __hip_bfloat16* vcb  = (__hip_bfloat16*)(wsb + 37748736);   // [4096,4,128]   4.19 MB
    __hip_bfloat16* Uw   = (__hip_bfloat16*)(wsb + 41943040);   // U^T then W^T  16.78 MB
    __hip_bfloat16* Zb   = (__hip_bfloat16*)(wsb + 58720256);   // GATE (fused GEMM -> rmsnorm) 16.78 MB
    float*          bcum = (float*)(wsb + 75497472);            // [64,16,64]     0.26 MB

    // Z (phase1 out / phase2 in) lives in the dead xbf slot.
    __hip_bfloat16* Zdelta = xbf;

    // BTall bf16 [5120][2048] = 20.97 MB lives in qcb+kcb (dead until convs;
    // GEMM completes before convs write qcb/kcb — stream-serialized).
    __hip_bfloat16* BTall = qcb;

    // --- d_out doubles as early scratch (dead before phase 2 writes O) ---
    char* dob = (char*)d_out;
    __hip_bfloat16* preQ = (__hip_bfloat16*)dob;                // [4096,2048] 16.78 MB
    __hip_bfloat16* preK = (__hip_bfloat16*)(dob + 16777216);   // [4096,512]   4.19 MB
    __hip_bfloat16* preV = (__hip_bfloat16*)(dob + 20971520);   // [4096,512]   4.19 MB
    float* bb = (float*)(dob + 25165824);                       // beta [4096,16]
    float* gb = (float*)(dob + 25427968);                       // g    [4096,16]
    __hip_bfloat16* WT32 = (__hip_bfloat16*)(dob + 25690112);   // packed Wb|Wgk bf16 [32,2048]
    float* Obuf = (float*)d_out;                                // fp32 O [4096,2048]

    const float qscale = 0.08838834764831845f; // D^-0.5
    const int nx = Mrows * DHc;

    f32_to_bf16<<<nx / 4 / 256, 256, 0, stream>>>(x, xbf, nx);
    pack_wt32<<<32, 256, 0, stream>>>(Wb, Wgk, WT32);
    proj_bg<<<64, 256, 0, stream>>>(xbf, WT32, A_log, dtb, bb, gb);
    bcum_kernel<<<64 * NCH, 64, 0, stream>>>(gb, bcum);

    // build BTall: rows 0-2047 Wq^T | 2048-2559 Wk^T | 2560-3071 Wv^T | 3072-5119 Wg^T
    transpose_to_bf16<<<dim3(32, 32), 256, 0, stream>>>(Wq, BTall, 2048, 2048);
    transpose_to_bf16<<<dim3(8, 32), 256, 0, stream>>>(Wk, BTall + (size_t)2048 * 2048, 2048, 512);
    transpose_to_bf16<<<dim3(8, 32), 256, 0, stream>>>(Wv, BTall + (size_t)2560 * 2048, 2048, 512);
    transpose_to_bf16<<<dim3(32, 32), 256, 0, stream>>>(Wg, BTall + (size_t)3072 * 2048, 2048, 2048);

    // fused q|k|v|gate projection (gate -> Zb; Zb is NOT touched again until rmsnorm)
    gemm_proj_fused<<<dim3(40, 32), 256, 0, stream>>>(xbf, BTall, preQ, preK, preV, Zb);

    conv_silu_norm<<<Mrows * HQc, 128, 0, stream>>>(preQ, cq, qcb, HQc, 1, qscale);
    conv_silu_norm<<<Mrows * HKc, 128, 0, stream>>>(preK, ck, kcb, HKc, 1, 1.0f);
    conv_silu_norm<<<Mrows * HKc, 128, 0, stream>>>(preV, cv, vcb, HKc, 0, 1.0f);

    // chunked delta-rule (Z in the dead xbf slot)
    gdn_phase1<<<64 * NCH, 256, 0, stream>>>(kcb, vcb, bb, bcum, Uw, Zdelta);
    gdn_phase2<<<256, 256, 0, stream>>>(qcb, kcb, Uw, Zdelta, bcum, Obuf);
    gdn_phase3<<<64 * NCH, 256, 0, stream>>>(qcb, kcb, Uw, bcum, Obuf);

    // rmsnorm (gate in Zb), output projection
    gated_rmsnorm<<<Mrows * Hc, 64, 0, stream>>>(Obuf, Zb, onw, qcb); // qcb dead after phase 3
    transpose_to_bf16<<<dim3(32, 32), 256, 0, stream>>>(Wo, (__hip_bfloat16*)Uw, 2048, 2048); // Uw dead after phase 3
    gemm_bt_bf16<<<dim3(16, 32), 256, 0, stream>>>(qcb, (__hip_bfloat16*)Uw, d_out, 2048, 2048, 0);
}

// Round 9
// 507.635 us; speedup vs baseline: 1.0639x; 1.0639x over previous
//
#include <hip/hip_runtime.h>
#include <hip/hip_bf16.h>
#include <math.h>

#define Bb 4
#define Ls 1024
#define DHc 2048
#define Dh 128
#define HQc 16
#define HKc 4
#define Hc 16
#define Mrows 4096   // Bb*Ls
#define CC 64        // chunk length
#define NCH 16       // chunks per sequence

typedef __attribute__((ext_vector_type(8))) short bf16x8;
typedef __attribute__((ext_vector_type(4))) float f32x4;

__device__ inline unsigned short f2b(float f) {
    __hip_bfloat16 h = __float2bfloat16(f);
    return *(unsigned short*)&h;
}
__device__ inline float b2f(unsigned short u) {
    __hip_bfloat16 h = *(__hip_bfloat16*)&u;
    return __bfloat162float(h);
}
__device__ inline bf16x8 scale_frag(bf16x8 a, float s) {
    union { bf16x8 v; unsigned short u[8]; } x;
    x.v = a;
#pragma unroll
    for (int i = 0; i < 8; i++) x.u[i] = f2b(b2f(x.u[i]) * s);
    return x.v;
}

// async global->LDS, 16B per lane; LDS dest is wave-uniform base + lane*16
__device__ inline void load_lds16(const void* g, void* l) {
    __builtin_amdgcn_global_load_lds((const __attribute__((address_space(1))) void*)g,
                                     (__attribute__((address_space(3))) void*)l, 16, 0, 0);
}

// LDS-only barrier: orders ds ops across waves WITHOUT draining vmcnt(0).
__device__ inline void bar_lds() {
    asm volatile("s_waitcnt lgkmcnt(0)" ::: "memory");
    __builtin_amdgcn_s_barrier();
    asm volatile("" ::: "memory");
}

// ---------------------------------------------------------------------------
// fp32 -> bf16 elementwise convert (n % 4 == 0)
// ---------------------------------------------------------------------------
__global__ void f32_to_bf16(const float* __restrict__ in, __hip_bfloat16* __restrict__ out, int n)
{
    int i = (blockIdx.x * 256 + threadIdx.x) * 4;
    if (i >= n) return;
    float4 v = *(const float4*)(in + i);
    __hip_bfloat16 h[4];
    h[0] = __float2bfloat16(v.x); h[1] = __float2bfloat16(v.y);
    h[2] = __float2bfloat16(v.z); h[3] = __float2bfloat16(v.w);
    *(uint2*)(out + i) = *(uint2*)h;
}

// ---------------------------------------------------------------------------
// Transpose + convert: W fp32 [Krows, Ncols] -> BT bf16 [Ncols, Krows].
// (kept for Wo, which must wait until Uw is dead after phase 3)
// ---------------------------------------------------------------------------
__launch_bounds__(256)
__global__ void transpose_to_bf16(const float* __restrict__ W, __hip_bfloat16* __restrict__ BT,
                                  int Krows, int Ncols)
{
    __shared__ float tile[64][65];
    const int n0 = blockIdx.x * 64, k0 = blockIdx.y * 64;
    const int tx = threadIdx.x & 63, ty = threadIdx.x >> 6;
#pragma unroll
    for (int r = ty; r < 64; r += 4)
        tile[r][tx] = W[(size_t)(k0 + r) * Ncols + n0 + tx];
    __syncthreads();
#pragma unroll
    for (int r = ty; r < 64; r += 4)
        BT[(size_t)(n0 + r) * Krows + k0 + tx] = __float2bfloat16(tile[tx][r]);
}

// ---------------------------------------------------------------------------
// All four input-side weight transposes in ONE dispatch (routing by block id):
// blocks [0,1024) Wq -> BTall rows 0-2047; [1024,1280) Wk -> rows 2048-2559;
// [1280,1536) Wv -> rows 2560-3071; [1536,2560) Wg -> rows 3072-5119.
// ---------------------------------------------------------------------------
__launch_bounds__(256)
__global__ void transpose_all_bf16(const float* __restrict__ Wq, const float* __restrict__ Wk,
                                   const float* __restrict__ Wv, const float* __restrict__ Wg,
                                   __hip_bfloat16* __restrict__ BTall)
{
    const int lb = blockIdx.x;
    const float* W; __hip_bfloat16* BT; int Ncols, bx, by;
    if (lb < 1024)      { W = Wq; BT = BTall;                          Ncols = 2048; int r = lb;        bx = r & 31; by = r >> 5; }
    else if (lb < 1280) { W = Wk; BT = BTall + (size_t)2048 * 2048;    Ncols = 512;  int r = lb - 1024; bx = r & 7;  by = r >> 3; }
    else if (lb < 1536) { W = Wv; BT = BTall + (size_t)2560 * 2048;    Ncols = 512;  int r = lb - 1280; bx = r & 7;  by = r >> 3; }
    else                { W = Wg; BT = BTall + (size_t)3072 * 2048;    Ncols = 2048; int r = lb - 1536; bx = r & 31; by = r >> 5; }

    __shared__ float tile[64][65];
    const int n0 = bx * 64, k0 = by * 64;
    const int tx = threadIdx.x & 63, ty = threadIdx.x >> 6;
#pragma unroll
    for (int r = ty; r < 64; r += 4)
        tile[r][tx] = W[(size_t)(k0 + r) * Ncols + n0 + tx];
    __syncthreads();
#pragma unroll
    for (int r = ty; r < 64; r += 4)
        BT[(size_t)(n0 + r) * 2048 + k0 + tx] = __float2bfloat16(tile[tx][r]);
}

// ---------------------------------------------------------------------------
// Out-projection GEMM, 128(M)x64(N) tiles, fp32 C: C = A @ BT^T.
// N=64 tiles double the grid (32x32 = 1024 blocks = 4/CU) vs the old 128x128
// (512 blocks = 2/CU) — the barrier-drain stall hides behind 2x more resident
// blocks (round-5 confirmed occupancy mechanism). Same slot-XOR swizzle.
// Per thread staging: 2 A-slots + 1 B-slot; per wave 8 MFMA/K-step (acc 4x2).
// ---------------------------------------------------------------------------
__launch_bounds__(256)
__global__ void gemm_bt_n64_f32(const __hip_bfloat16* __restrict__ A, const __hip_bfloat16* __restrict__ BT,
                                float* __restrict__ C, int N, int K)
{
    __shared__ __align__(16) unsigned short As[128 * 32];  // 8 KB
    __shared__ __align__(16) unsigned short Bs[64 * 32];   // 4 KB
    const int tid = threadIdx.x;
    const int lane = tid & 63;
    const int wave = tid >> 6;
    const int wm = (wave >> 1) * 64, wn = (wave & 1) * 32;
    const int row0 = blockIdx.y * 128, col0 = blockIdx.x * 64;

    // staging rows: wave w covers rows 16w..16w+15 per chunk (lane>>2 in-stripe)
    const int rA0 = wave * 16 + (lane >> 2);          // A rows 0..63
    const int rA1 = 64 + wave * 16 + (lane >> 2);     // A rows 64..127
    const int rB  = wave * 16 + (lane >> 2);          // B rows 0..63
    const int kk = ((lane & 3) ^ ((lane >> 3) & 3)) * 8;   // swizzled source slot
    const __hip_bfloat16* Ap0 = A + (size_t)(row0 + rA0) * K + kk;
    const __hip_bfloat16* Ap1 = A + (size_t)(row0 + rA1) * K + kk;
    const __hip_bfloat16* Bp0 = BT + (size_t)(col0 + rB) * K + kk;
    unsigned short* sa0 = &As[(wave * 16) * 32];           // wave-uniform dests
    unsigned short* sa1 = &As[(64 + wave * 16) * 32];
    unsigned short* sb0 = &Bs[(wave * 16) * 32];

    f32x4 acc[4][2];
#pragma unroll
    for (int i = 0; i < 4; i++)
#pragma unroll
        for (int j = 0; j < 2; j++) acc[i][j] = (f32x4){0.f, 0.f, 0.f, 0.f};

    const int fr = lane & 15;
    const int fs = (((lane >> 4) ^ ((fr >> 1) & 3))) * 8;  // swizzled read slot

    for (int k0 = 0; k0 < K; k0 += 32) {
        __syncthreads();
        load_lds16(Ap0, sa0);
        load_lds16(Ap1, sa1);
        load_lds16(Bp0, sb0);
        Ap0 += 32; Ap1 += 32; Bp0 += 32;
        __syncthreads();

        bf16x8 af[4], bfr[2];
#pragma unroll
        for (int i = 0; i < 4; i++)
            af[i] = *(const bf16x8*)&As[(wm + i * 16 + fr) * 32 + fs];
#pragma unroll
        for (int j = 0; j < 2; j++)
            bfr[j] = *(const bf16x8*)&Bs[(wn + j * 16 + fr) * 32 + fs];
#pragma unroll
        for (int i = 0; i < 4; i++)
#pragma unroll
            for (int j = 0; j < 2; j++)
                acc[i][j] = __builtin_amdgcn_mfma_f32_16x16x32_bf16(af[i], bfr[j], acc[i][j], 0, 0, 0);
    }

    const int cr = (lane >> 4) * 4;
    const int cc = lane & 15;
#pragma unroll
    for (int i = 0; i < 4; i++)
#pragma unroll
        for (int j = 0; j < 2; j++) {
            size_t base = (size_t)(row0 + wm + i * 16 + cr) * N + (col0 + wn + j * 16 + cc);
#pragma unroll
            for (int p = 0; p < 4; p++)
                C[base + (size_t)p * N] = acc[i][j][p];
        }
}

// ---------------------------------------------------------------------------
// Fused projection GEMM: [4096,2048] @ BTall[5120,2048]^T, C routed per
// col-block. Grid 40x32 = 1280 blocks = 5/CU. Slot-XOR swizzled LDS
// (bank conflicts measured 0 after r8).
// ---------------------------------------------------------------------------
__launch_bounds__(256)
__global__ void gemm_proj_fused(const __hip_bfloat16* __restrict__ A, const __hip_bfloat16* __restrict__ BT,
                                __hip_bfloat16* __restrict__ preQ, __hip_bfloat16* __restrict__ preK,
                                __hip_bfloat16* __restrict__ preV, __hip_bfloat16* __restrict__ gate)
{
    const int K = 2048;
    __shared__ __align__(16) unsigned short As[128 * 32];
    __shared__ __align__(16) unsigned short Bs[128 * 32];
    const int tid = threadIdx.x;
    const int lane = tid & 63;
    const int wave = tid >> 6;
    const int wm = (wave >> 1) * 64, wn = (wave & 1) * 64;
    const int row0 = blockIdx.y * 128;
    const int cb = blockIdx.x;           // 0..39
    const int col0 = cb * 128;           // BTall row base

    // C routing (uniform per block)
    __hip_bfloat16* Cb; int Nloc, c0loc;
    if (cb < 16)      { Cb = preQ; Nloc = 2048; c0loc = cb * 128; }
    else if (cb < 20) { Cb = preK; Nloc = 512;  c0loc = (cb - 16) * 128; }
    else if (cb < 24) { Cb = preV; Nloc = 512;  c0loc = (cb - 20) * 128; }
    else              { Cb = gate; Nloc = 2048; c0loc = (cb - 24) * 128; }

    const int r0 = (wave * 2 + 0) * 16 + (lane >> 2);
    const int r1 = (wave * 2 + 1) * 16 + (lane >> 2);
    const int kk = ((lane & 3) ^ ((lane >> 3) & 3)) * 8;   // swizzled source slot
    const __hip_bfloat16* Ap0 = A + (size_t)(row0 + r0) * K + kk;
    const __hip_bfloat16* Ap1 = A + (size_t)(row0 + r1) * K + kk;
    const __hip_bfloat16* Bp0 = BT + (size_t)(col0 + r0) * K + kk;
    const __hip_bfloat16* Bp1 = BT + (size_t)(col0 + r1) * K + kk;
    unsigned short* sa0 = &As[(wave * 2 + 0) * 16 * 32];
    unsigned short* sa1 = &As[(wave * 2 + 1) * 16 * 32];
    unsigned short* sb0 = &Bs[(wave * 2 + 0) * 16 * 32];
    unsigned short* sb1 = &Bs[(wave * 2 + 1) * 16 * 32];

    f32x4 acc[4][4];
#pragma unroll
    for (int i = 0; i < 4; i++)
#pragma unroll
        for (int j = 0; j < 4; j++) acc[i][j] = (f32x4){0.f, 0.f, 0.f, 0.f};

    const int fr = lane & 15;
    const int fs = (((lane >> 4) ^ ((fr >> 1) & 3))) * 8;  // swizzled read slot

    for (int k0 = 0; k0 < K; k0 += 32) {
        __syncthreads();
        load_lds16(Ap0, sa0);
        load_lds16(Ap1, sa1);
        load_lds16(Bp0, sb0);
        load_lds16(Bp1, sb1);
        Ap0 += 32; Ap1 += 32; Bp0 += 32; Bp1 += 32;
        __syncthreads();

        bf16x8 af[4], bfr[4];
#pragma unroll
        for (int i = 0; i < 4; i++)
            af[i] = *(const bf16x8*)&As[(wm + i * 16 + fr) * 32 + fs];
#pragma unroll
        for (int j = 0; j < 4; j++)
            bfr[j] = *(const bf16x8*)&Bs[(wn + j * 16 + fr) * 32 + fs];
#pragma unroll
        for (int i = 0; i < 4; i++)
#pragma unroll
            for (int j = 0; j < 4; j++)
                acc[i][j] = __builtin_amdgcn_mfma_f32_16x16x32_bf16(af[i], bfr[j], acc[i][j], 0, 0, 0);
    }

    const int cr = (lane >> 4) * 4;
    const int cc = lane & 15;
#pragma unroll
    for (int i = 0; i < 4; i++)
#pragma unroll
        for (int j = 0; j < 4; j++) {
            size_t base = (size_t)(row0 + wm + i * 16 + cr) * Nloc + (c0loc + wn + j * 16 + cc);
#pragma unroll
            for (int p = 0; p < 4; p++)
                Cb[base + (size_t)p * Nloc] = __float2bfloat16(acc[i][j][p]);
        }
}

// ---------------------------------------------------------------------------
// Causal depthwise conv (K=4) + SiLU + optional l2norm(+scale). bf16 in/out.
// ---------------------------------------------------------------------------
__global__ void conv_silu_norm(const __hip_bfloat16* __restrict__ pre, const float* __restrict__ w,
                               __hip_bfloat16* __restrict__ out, int NH, int do_norm, float scale)
{
    __shared__ float red[2];
    const int idx = blockIdx.x;
    const int head = idx % NH;
    const int l = (idx / NH) % Ls;
    const int b = idx / (NH * Ls);
    const int C = NH * Dh;
    const int c = head * Dh + threadIdx.x;
    const __hip_bfloat16* base = pre + ((size_t)b * Ls + l) * C + c;
    const float4 wv = *(const float4*)(w + (size_t)c * 4);

    float v0 = (l >= 3) ? __bfloat162float(base[-3 * C]) : 0.f;
    float v1 = (l >= 2) ? __bfloat162float(base[-2 * C]) : 0.f;
    float v2 = (l >= 1) ? __bfloat162float(base[-1 * C]) : 0.f;
    float v3 = __bfloat162float(base[0]);
    float y = v0 * wv.x + v1 * wv.y + v2 * wv.z + v3 * wv.w;
    y = y / (1.f + expf(-y));   // SiLU

    if (do_norm) {
        float ss = y * y;
#pragma unroll
        for (int off = 32; off > 0; off >>= 1) ss += __shfl_xor(ss, off);
        if ((threadIdx.x & 63) == 0) red[threadIdx.x >> 6] = ss;
        __syncthreads();
        float tot = red[0] + red[1];
        y = y * rsqrtf(tot + 1e-6f) * scale;
    }
    out[((size_t)b * Ls + l) * C + c] = __float2bfloat16(y);
}

// ---------------------------------------------------------------------------
// Pack Wb,Wgk fp32 [2048][16] -> WT32 bf16 [32][2048] (rows 0-15 Wb^T, 16-31 Wgk^T)
// ---------------------------------------------------------------------------
__global__ void pack_wt32(const float* __restrict__ Wb, const float* __restrict__ Wgk,
                          __hip_bfloat16* __restrict__ WT)
{
    const int t = blockIdx.x * 64 + (threadIdx.x & 63);
    const int h0 = (threadIdx.x >> 6) * 4;
#pragma unroll
    for (int i = 0; i < 4; i++) {
        const int h = h0 + i;
        WT[(size_t)h * 2048 + t]        = __float2bfloat16(Wb[(size_t)t * 16 + h]);
        WT[(size_t)(16 + h) * 2048 + t] = __float2bfloat16(Wgk[(size_t)t * 16 + h]);
    }
}

// ---------------------------------------------------------------------------
// beta/g via MFMA skinny GEMM over xbf: [4096,2048]@[2048,32].
// ---------------------------------------------------------------------------
__launch_bounds__(256)
__global__ void proj_bg(const __hip_bfloat16* __restrict__ xbf, const __hip_bfloat16* __restrict__ WT32,
                        const float* __restrict__ A_log, const float* __restrict__ dt_bias,
                        float* __restrict__ beta, float* __restrict__ g)
{
    const int tid = threadIdx.x;
    const int lane = tid & 63;
    const int wave = tid >> 6;
    const int q = lane >> 4;     // 0..3 (k-subgroup)
    const int cL = lane & 15;    // 0..15 (A-row / B-col within frag)
    const int row0 = blockIdx.x * 64 + wave * 16;

    const unsigned short* xu = (const unsigned short*)xbf;
    const unsigned short* wu = (const unsigned short*)WT32;

    f32x4 accB = (f32x4){0.f, 0.f, 0.f, 0.f};
    f32x4 accG = (f32x4){0.f, 0.f, 0.f, 0.f};
    const size_t arow = (size_t)(row0 + cL) * 2048;
    const size_t brow = (size_t)cL * 2048;         // Wb^T head cL
    const size_t grow = (size_t)(16 + cL) * 2048;  // Wgk^T head cL

#pragma unroll 4
    for (int k = 0; k < 2048; k += 32) {
        bf16x8 af  = *(const bf16x8*)&xu[arow + k + q * 8];
        bf16x8 wbf = *(const bf16x8*)&wu[brow + k + q * 8];
        bf16x8 wgf = *(const bf16x8*)&wu[grow + k + q * 8];
        accB = __builtin_amdgcn_mfma_f32_16x16x32_bf16(af, wbf, accB, 0, 0, 0);
        accG = __builtin_amdgcn_mfma_f32_16x16x32_bf16(af, wgf, accG, 0, 0, 0);
    }

    // C layout: row = 4q+p (block-local), col = cL (head)
    const float al = __expf(A_log[cL]);
    const float db = dt_bias[cL];
#pragma unroll
    for (int p = 0; p < 4; p++) {
        const int r = row0 + 4 * q + p;
        beta[(size_t)r * 16 + cL] = 1.f / (1.f + __expf(-accB[p]));
        float z = accG[p] + db;
        float sp = (z > 20.f) ? z : log1pf(__expf(z));
        g[(size_t)r * 16 + cL] = -al * sp;
    }
}

// ---------------------------------------------------------------------------
// Per-chunk inclusive prefix sum of log-decay g. grid = BH*NCH blocks, 64 thr.
// ---------------------------------------------------------------------------
__global__ void bcum_kernel(const float* __restrict__ g, float* __restrict__ bcum)
{
    const int c = blockIdx.x & 15;
    const int bh = blockIdx.x >> 4;
    const int b = bh >> 4;
    const int h = bh & 15;
    const int t = threadIdx.x;
    float v = g[((size_t)(b * Ls + c * CC + t)) * 16 + h];
#pragma unroll
    for (int d = 1; d < 64; d <<= 1) {
        float n = __shfl_up(v, d, 64);
        if (t >= d) v += n;
    }
    bcum[(size_t)blockIdx.x * 64 + t] = v;
}

// ---------------------------------------------------------------------------
// Phase 1 (parallel over 1024 (b,h,chunk) tasks):
//   P = K K^T (MFMA); A[t][s] = beta_t exp(bc_t-bc_s) P (s<t);
//   forward-substitute (I+A)[U|Z] = [diag(beta)V | diag(beta)diag(exp(bc))K]
// U stored TRANSPOSED ([v][t], stride 64) == layout phase 2 overwrites with
// W^T (race fix). Z goes to the DEAD xbf slot (gate occupies Zb).
// ---------------------------------------------------------------------------
__launch_bounds__(256)
__global__ void gdn_phase1(const __hip_bfloat16* __restrict__ kc, const __hip_bfloat16* __restrict__ vc,
                           const float* __restrict__ bb, const float* __restrict__ bcum,
                           __hip_bfloat16* __restrict__ U, __hip_bfloat16* __restrict__ Z)
{
    const int task = blockIdx.x;
    const int c = task & 15;
    const int bh = task >> 4;
    const int b = bh >> 4;
    const int h = bh & 15;
    const int hk = h >> 2;
    const int tid = threadIdx.x;
    const int lane = tid & 63;
    const int wave = tid >> 6;
    const int q = lane >> 4;
    const int cL = lane & 15;

    __shared__ float Ab[64][68];
    __shared__ float sbeta[64], sbc[64];

    if (tid < 64) {
        sbeta[tid] = bb[((size_t)(b * Ls + c * CC + tid)) * 16 + h];
        sbc[tid] = bcum[((size_t)bh * 16 + c) * 64 + tid];
    }
    __syncthreads();

    const unsigned short* ku = (const unsigned short*)kc;
    const unsigned short* vu = (const unsigned short*)vc;

    // P = K K^T : wave w owns rows t in [16w,16w+16)
    f32x4 pacc[4];
#pragma unroll
    for (int j = 0; j < 4; j++) pacc[j] = (f32x4){0.f, 0.f, 0.f, 0.f};
    {
        const int t = 16 * wave + cL;
        const size_t krow = (((size_t)(b * Ls + c * CC + t)) * 4 + hk) * 128;
#pragma unroll
        for (int ks = 0; ks < 4; ks++) {
            bf16x8 af = *(const bf16x8*)&ku[krow + ks * 32 + q * 8];
#pragma unroll
            for (int j = 0; j < 4; j++) {
                const int s = 16 * j + cL;
                bf16x8 bf = *(const bf16x8*)&ku[(((size_t)(b * Ls + c * CC + s)) * 4 + hk) * 128 + ks * 32 + q * 8];
                pacc[j] = __builtin_amdgcn_mfma_f32_16x16x32_bf16(af, bf, pacc[j], 0, 0, 0);
            }
        }
    }
    // dump A (fp32, zero on/above diagonal)
#pragma unroll
    for (int j = 0; j < 4; j++)
#pragma unroll
        for (int p = 0; p < 4; p++) {
            const int t = 16 * wave + 4 * q + p;
            const int s = 16 * j + cL;
            float val = 0.f;
            if (s < t) val = sbeta[t] * __expf(sbc[t] - sbc[s]) * pacc[j][p];
            Ab[t][s] = val;
        }
    __syncthreads();

    // forward substitution, thread = one column of [U | Z]
    float u[64];
    const int j = tid;
    if (j < 128) {
#pragma unroll
        for (int t = 0; t < 64; t++)
            u[t] = sbeta[t] * b2f(vu[(((size_t)(b * Ls + c * CC + t)) * 4 + hk) * 128 + j]);
    } else {
        const int k = j - 128;
#pragma unroll
        for (int t = 0; t < 64; t++)
            u[t] = sbeta[t] * __expf(sbc[t]) * b2f(ku[(((size_t)(b * Ls + c * CC + t)) * 4 + hk) * 128 + k]);
    }
#pragma unroll
    for (int t = 1; t < 64; t++) {
        const float4* ar = (const float4*)Ab[t];
        const int nf = (t + 3) >> 2;
        float a0 = 0.f, a1 = 0.f, a2 = 0.f, a3 = 0.f;
#pragma unroll
        for (int i = 0; i < nf; i++) {
            float4 av = ar[i];
            a0 = fmaf(av.x, u[4 * i + 0], a0);
            a1 = fmaf(av.y, u[4 * i + 1], a1);
            a2 = fmaf(av.z, u[4 * i + 2], a2);
            a3 = fmaf(av.w, u[4 * i + 3], a3);
        }
        u[t] -= (a0 + a1) + (a2 + a3);
    }
    const size_t slab = ((size_t)bh * 16 + c) * 8192;
    if (j < 128) {
        // U^T store: thread j owns v-column j -> contiguous 64 ushorts = 8x16B
        unsigned short* Up = (unsigned short*)U + slab + (size_t)j * 64;
#pragma unroll
        for (int t8 = 0; t8 < 8; t8++) {
            union { bf16x8 v; unsigned short us[8]; } pk;
#pragma unroll
            for (int e = 0; e < 8; e++) pk.us[e] = f2b(u[8 * t8 + e]);
            *(bf16x8*)&Up[t8 * 8] = pk.v;
        }
    } else {
#pragma unroll
        for (int t = 0; t < 64; t++) Z[slab + t * 128 + (j - 128)] = __float2bfloat16(u[t]);
    }
}

// ---------------------------------------------------------------------------
// Phase 2 v4: sequential over 16 chunks; 256 blocks = (b,h) x 4 v-QUARTERS.
// Block owns 32 v-columns of state T[v][k]:
//   per chunk: W = U - Z T^T ; O1 = Q T^T (row-scaled exp(bc_t) in epilogue)
//   ; T = eC T + W^T K_hat
// Barriers are lgkmcnt-only (LDS deps); global deps register-carried.
// ---------------------------------------------------------------------------
__launch_bounds__(256, 1)
__global__ void gdn_phase2(const __hip_bfloat16* __restrict__ qc, const __hip_bfloat16* __restrict__ kc,
                           __hip_bfloat16* Uw /* in: U^T, out: W^T (aliased) */,
                           const __hip_bfloat16* __restrict__ Zbuf,
                           const float* __restrict__ bcum, float* __restrict__ Obuf)
{
    const int blk = blockIdx.x;
    const int quarter = blk & 3;
    const int bh = blk >> 2;
    const int b = bh >> 4;
    const int h = bh & 15;
    const int hk = h >> 2;
    const int vbase = quarter * 32;
    const int tid = threadIdx.x;
    const int lane = tid & 63;
    const int wave = tid >> 6;
    const int q = lane >> 4;
    const int cL = lane & 15;

    // LDS tiles
    __shared__ __align__(16) unsigned short Tb[32 * 136]; // T as B-frag: [vloc][k]
    __shared__ __align__(16) unsigned short Kt[128 * 72]; // K_hat^T: [k][tloc]
    __shared__ __align__(16) unsigned short Wt[32 * 72];  // W^T: [vloc][t]
    __shared__ __align__(16) unsigned short Us[32 * 72];  // U^T: [vloc][t]

    const unsigned short* qu = (const unsigned short*)qc;
    const unsigned short* ku = (const unsigned short*)kc;
    unsigned short* Uu = (unsigned short*)Uw;
    const unsigned short* Zu = (const unsigned short*)Zbuf;

    const int tloc = tid & 63;          // staging row (t for K, etc.)
    const int kg = tid >> 6;            // k-group for K staging
    const int trow = 16 * wave + cL;    // A-frag row (chunk-local t) for G1/G2
    const int wv = (wave & 1) * 16;     // wave's v-row base within quarter (G3)
    const int wk = (wave >> 1) * 4;     // wave's k-tile base (G3), tiles of 16

    // state accumulators: wave owns v in [wv,wv+16), k in [64*(wave>>1),+64)
    f32x4 Tacc[4];
#pragma unroll
    for (int j = 0; j < 4; j++) Tacc[j] = (f32x4){0.f, 0.f, 0.f, 0.f};

    // ---- prefetch registers (chunk c+1 loaded during chunk c) ----
    bf16x8 Kreg[4], Zreg[4], Qreg[4];
    uint4 Ureg;
    float p_bctl, p_bc63;
    float4 p_bct4;

    auto prefetch = [&](int c) {
        const size_t base_t = (size_t)b * Ls + (size_t)c * CC;
        const size_t slab = ((size_t)bh * 16 + c) * 8192;
        const size_t krow = ((base_t + tloc) * 4 + hk) * 128 + 32 * kg;
#pragma unroll
        for (int m = 0; m < 4; m++) Kreg[m] = *(const bf16x8*)&ku[krow + m * 8];
        // U^T quarter: row v = vbase + (tid>>3), cols t = (tid&7)*8 .. +7
        Ureg = *(const uint4*)&Uu[slab + (size_t)(vbase + (tid >> 3)) * 64 + (tid & 7) * 8];
        const size_t zrow = slab + (size_t)trow * 128;
        const size_t qrow = ((base_t + trow) * 16 + h) * 128;
#pragma unroll
        for (int ks = 0; ks < 4; ks++) {
            Zreg[ks] = *(const bf16x8*)&Zu[zrow + ks * 32 + q * 8];
            Qreg[ks] = *(const bf16x8*)&qu[qrow + ks * 32 + q * 8];
        }
        const float* bc = bcum + ((size_t)bh * 16 + c) * 64;
        p_bctl = bc[tloc];
        p_bc63 = bc[63];
        p_bct4 = *(const float4*)&bc[16 * wave + 4 * q];  // bc at t=16w+4q+p
    };

    prefetch(0);

    for (int c = 0; c < NCH; ++c) {
        // consume prefetched values into locals
        bf16x8 kr[4], zr[4], qr[4];
        uint4 ur;
#pragma unroll
        for (int m = 0; m < 4; m++) { kr[m] = Kreg[m]; zr[m] = Zreg[m]; qr[m] = Qreg[m]; }
        ur = Ureg;
        const float bctl = p_bctl, bc63 = p_bc63;
        const float4 bct4 = p_bct4;
        const size_t slab = ((size_t)bh * 16 + c) * 8192;

        // issue next chunk's global loads now (land during this chunk's compute)
        if (c + 1 < NCH) prefetch(c + 1);

        const float ek = __expf(bc63 - bctl);   // K_hat row scale (my tloc)
        const float eC = __expf(bc63);          // full-chunk decay

        bar_lds();  // barrier 1: prev chunk readers of Tb/Kt/Us/Wt done

        // stage K_hat^T: rows k=32kg+8m+e, col tloc
#pragma unroll
        for (int m = 0; m < 4; m++) {
            union { bf16x8 v; unsigned short us[8]; } kv;
            kv.v = scale_frag(kr[m], ek);
#pragma unroll
            for (int e = 0; e < 8; e++) Kt[(32 * kg + 8 * m + e) * 72 + tloc] = kv.us[e];
        }
        // stage U^T quarter: [vloc][t]
        *(uint4*)&Us[(tid >> 3) * 72 + (tid & 7) * 8] = ur;
        // dump T into Tb: row v=wv+4q+p, col k=64*(wave>>1)+16j+cL
#pragma unroll
        for (int j = 0; j < 4; j++)
#pragma unroll
            for (int p = 0; p < 4; p++)
                Tb[(wv + 4 * q + p) * 136 + (wave >> 1) * 64 + 16 * j + cL] = f2b(Tacc[j][p]);

        bar_lds();  // barrier 2: staging visible

        // G1: W' = Z T^T ; G2: O1 = Q T^T   (output [t][v], 16x16 tiles)
        f32x4 Wacc[2], Oacc[2];
#pragma unroll
        for (int j = 0; j < 2; j++) { Wacc[j] = (f32x4){0.f,0.f,0.f,0.f}; Oacc[j] = (f32x4){0.f,0.f,0.f,0.f}; }
#pragma unroll
        for (int ks = 0; ks < 4; ks++) {
#pragma unroll
            for (int j = 0; j < 2; j++) {
                bf16x8 bt = *(const bf16x8*)&Tb[(16 * j + cL) * 136 + 32 * ks + 8 * q];
                Wacc[j] = __builtin_amdgcn_mfma_f32_16x16x32_bf16(zr[ks], bt, Wacc[j], 0, 0, 0);
                Oacc[j] = __builtin_amdgcn_mfma_f32_16x16x32_bf16(qr[ks], bt, Oacc[j], 0, 0, 0);
            }
        }
        // epilogue: W = U - W'; dump W^T; store O1*exp(bc_t) (fp32 row scale)
        float e4[4] = {__expf(bct4.x), __expf(bct4.y), __expf(bct4.z), __expf(bct4.w)};
#pragma unroll
        for (int j = 0; j < 2; j++)
#pragma unroll
            for (int p = 0; p < 4; p++) {
                const int t = 16 * wave + 4 * q + p;
                const int v = 16 * j + cL;
                const float w = b2f(Us[v * 72 + t]) - Wacc[j][p];
                Wt[v * 72 + t] = f2b(w);
                Obuf[((size_t)b * Ls + c * CC + t) * 2048 + h * 128 + vbase + v] = Oacc[j][p] * e4[p];
            }

        bar_lds();  // barrier 3: Wt complete

        // store W^T to global over U slab (phase 3 layout: [vglobal][t], stride 64)
        {
            const int vloc = tid >> 3, part = tid & 7;
            const size_t dst = slab + (size_t)(vbase + vloc) * 64 + part * 8;
            *(uint4*)&Uu[dst] = *(const uint4*)&Wt[vloc * 72 + part * 8];
        }
        // G3: T = eC*T + W^T K_hat  (output [v][k]; wave's 16v x 64k region)
#pragma unroll
        for (int j = 0; j < 4; j++)
#pragma unroll
            for (int p = 0; p < 4; p++) Tacc[j][p] *= eC;
#pragma unroll
        for (int ks = 0; ks < 2; ks++) {
            bf16x8 aw = *(const bf16x8*)&Wt[(wv + cL) * 72 + 32 * ks + 8 * q];
#pragma unroll
            for (int j = 0; j < 4; j++) {
                bf16x8 bk = *(const bf16x8*)&Kt[((wk + j) * 16 + cL) * 72 + 32 * ks + 8 * q];
                Tacc[j] = __builtin_amdgcn_mfma_f32_16x16x32_bf16(aw, bk, Tacc[j], 0, 0, 0);
            }
        }
    }
}

// ---------------------------------------------------------------------------
// Phase 3 (parallel over 1024 (b,h,chunk) tasks), now with FUSED gated
// RMSNorm epilogue:
//   M[t][s] = exp(bc_t-bc_s) (q_t.k_s), s<=t;  O2 = M W;
//   O = Obuf(O1) + O2;  out = O*rsqrt(mean(O^2)+eps)*w*silu(gate)  -> nrm
// Works because for fixed row t, the full v=0..127 lives in ONE 16-lane
// group (wave=t>>4, q=(t&15)>>2; 16 cL-lanes x 8 j-regs): the row reduce is
// 4 shfl_xor (masks 1,2,4,8 = cL bits). Kills the 33.5MB Obuf O2-write and
// the separate gated_rmsnorm dispatch. Output goes to nrm (dead-Z slot), NOT
// qcb, so no aliasing with the Q input.
// ---------------------------------------------------------------------------
__launch_bounds__(256)
__global__ void gdn_phase3(const __hip_bfloat16* __restrict__ qc, const __hip_bfloat16* __restrict__ kc,
                           const __hip_bfloat16* __restrict__ WT, const float* __restrict__ bcum,
                           const float* __restrict__ Obuf, const __hip_bfloat16* __restrict__ gate,
                           const float* __restrict__ onw, __hip_bfloat16* __restrict__ nrm)
{
    const int task = blockIdx.x;
    const int c = task & 15;
    const int bh = task >> 4;
    const int b = bh >> 4;
    const int h = bh & 15;
    const int hk = h >> 2;
    const int tid = threadIdx.x;
    const int lane = tid & 63;
    const int wave = tid >> 6;
    const int q = lane >> 4;
    const int cL = lane & 15;

    __shared__ __align__(16) unsigned short Mb[64 * 72];
    __shared__ float sbc[64];

    if (tid < 64) sbc[tid] = bcum[((size_t)bh * 16 + c) * 64 + tid];
    __syncthreads();

    const unsigned short* qu = (const unsigned short*)qc;
    const unsigned short* ku = (const unsigned short*)kc;
    const unsigned short* wu = (const unsigned short*)WT;
    const unsigned short* gu = (const unsigned short*)gate;
    unsigned short* nu = (unsigned short*)nrm;

    // Pq = Q K^T
    f32x4 pacc[4];
#pragma unroll
    for (int j = 0; j < 4; j++) pacc[j] = (f32x4){0.f, 0.f, 0.f, 0.f};
    {
        const int t = 16 * wave + cL;
        const size_t qrow = (((size_t)(b * Ls + c * CC + t)) * 16 + h) * 128;
#pragma unroll
        for (int ks = 0; ks < 4; ks++) {
            bf16x8 aq = *(const bf16x8*)&qu[qrow + ks * 32 + q * 8];
#pragma unroll
            for (int j = 0; j < 4; j++) {
                const int s = 16 * j + cL;
                bf16x8 bk = *(const bf16x8*)&ku[(((size_t)(b * Ls + c * CC + s)) * 4 + hk) * 128 + ks * 32 + q * 8];
                pacc[j] = __builtin_amdgcn_mfma_f32_16x16x32_bf16(aq, bk, pacc[j], 0, 0, 0);
            }
        }
    }
#pragma unroll
    for (int j = 0; j < 4; j++)
#pragma unroll
        for (int p = 0; p < 4; p++) {
            const int t = 16 * wave + 4 * q + p;
            const int s = 16 * j + cL;
            const float val = (s <= t) ? __expf(sbc[t] - sbc[s]) * pacc[j][p] : 0.f;
            Mb[t * 72 + s] = f2b(val);
        }
    __syncthreads();

    // O2 = M W ; B-frags from W^T (global, contiguous)
    f32x4 oacc[8];
#pragma unroll
    for (int j = 0; j < 8; j++) oacc[j] = (f32x4){0.f, 0.f, 0.f, 0.f};
    const size_t slab = ((size_t)bh * 16 + c) * 8192;
#pragma unroll
    for (int ks = 0; ks < 2; ks++) {
        bf16x8 am = *(const bf16x8*)&Mb[(16 * wave + cL) * 72 + ks * 32 + q * 8];
#pragma unroll
        for (int j = 0; j < 8; j++) {
            const int v = 16 * j + cL;
            bf16x8 bw = *(const bf16x8*)&wu[slab + (size_t)v * 64 + ks * 32 + q * 8];
            oacc[j] = __builtin_amdgcn_mfma_f32_16x16x32_bf16(am, bw, oacc[j], 0, 0, 0);
        }
    }

    // fused gated RMSNorm epilogue (one row t per p; row fully in 16-lane group)
#pragma unroll
    for (int p = 0; p < 4; p++) {
        const int t = 16 * wave + 4 * q + p;
        const size_t l = (size_t)(b * Ls + c * CC + t);
        const size_t orow = l * 2048 + (size_t)h * 128;   // Obuf (O1) row
        const size_t xrow = (l * 16 + h) * 128;           // gate / output row
        float ov[8];
        float ss = 0.f;
#pragma unroll
        for (int j = 0; j < 8; j++) {
            const int v = 16 * j + cL;
            ov[j] = Obuf[orow + v] + oacc[j][p];
            ss += ov[j] * ov[j];
        }
#pragma unroll
        for (int m = 1; m < 16; m <<= 1) ss += __shfl_xor(ss, m);
        const float r = rsqrtf(ss * (1.f / 128.f) + 1e-5f);
#pragma unroll
        for (int j = 0; j < 8; j++) {
            const int v = 16 * j + cL;
            const float gv = b2f(gu[xrow + v]);
            nu[xrow + v] = f2b(ov[j] * r * onw[v] * (gv / (1.f + __expf(-gv))));
        }
    }
}

// ---------------------------------------------------------------------------
extern "C" void kernel_launch(void* const* d_in, const int* in_sizes, int n_in,
                              void* d_out, int out_size, void* d_ws, size_t ws_size,
                              hipStream_t stream)
{
    const float* x     = (const float*)d_in[0];
    const float* Wq    = (const float*)d_in[1];
    const float* Wk    = (const float*)d_in[2];
    const float* Wv    = (const float*)d_in[3];
    const float* Wb    = (const float*)d_in[4];
    const float* Wgk   = (const float*)d_in[5];
    const float* A_log = (const float*)d_in[6];
    const float* dtb   = (const float*)d_in[7];
    const float* cq    = (const float*)d_in[8];
    const float* ck    = (const float*)d_in[9];
    const float* cv    = (const float*)d_in[10];
    const float* Wg    = (const float*)d_in[11];
    const float* onw   = (const float*)d_in[12];
    const float* Wo    = (const float*)d_in[13];

    // --- workspace layout (bytes), total 75,759,616 B ---
    char* wsb = (char*)d_ws;
    __hip_bfloat16* xbf  = (__hip_bfloat16*)(wsb + 0);          // [4096,2048] 16.78 MB; DEAD after
                                                                // gemm_proj_fused -> Z -> nrm
    __hip_bfloat16* qcb  = (__hip_bfloat16*)(wsb + 16777216);   // [4096,16,128] 16.78 MB
    __hip_bfloat16* kcb  = (__hip_bfloat16*)(wsb + 33554432);   // [4096,4,128]   4.19 MB
    __hip_bfloat16* vcb  = (__hip_bfloat16*)(wsb + 37748736);   // [4096,4,128]   4.19 MB
    __hip_bfloat16* Uw   = (__hip_bfloat16*)(wsb + 41943040);   // U^T then W^T  16.78 MB
    __hip_bfloat16* Zb   = (__hip_bfloat16*)(wsb + 58720256);   // GATE (fused GEMM -> phase3) 16.78 MB
    float*          bcum = (float*)(wsb + 75497472);            // [64,16,64]     0.26 MB

    // xbf slot reuse chain: xbf (until fused GEMM) -> Zdelta (phase1->phase2)
    // -> nrm (phase3 normalized output -> out-proj A)
    __hip_bfloat16* Zdelta = xbf;
    __hip_bfloat16* nrm    = xbf;

    // BTall bf16 [5120][2048] = 20.97 MB lives in qcb+kcb (dead until convs).
    __hip_bfloat16* BTall = qcb;

    // --- d_out doubles as early scratch (dead before phase 2 writes O) ---
    char* dob = (char*)d_out;
    __hip_bfloat16* preQ = (__hip_bfloat16*)dob;                // [4096,2048] 16.78 MB
    __hip_bfloat16* preK = (__hip_bfloat16*)(dob + 16777216);   // [4096,512]   4.19 MB
    __hip_bfloat16* preV = (__hip_bfloat16*)(dob + 20971520);   // [4096,512]   4.19 MB
    float* bb = (float*)(dob + 25165824);                       // beta [4096,16]
    float* gb = (float*)(dob + 25427968);                       // g    [4096,16]
    __hip_bfloat16* WT32 = (__hip_bfloat16*)(dob + 25690112);   // packed Wb|Wgk bf16 [32,2048]
    float* Obuf = (float*)d_out;                                // fp32 O1 [4096,2048] (phase2 out, phase3 in)

    const float qscale = 0.08838834764831845f; // D^-0.5
    const int nx = Mrows * DHc;

    f32_to_bf16<<<nx / 4 / 256, 256, 0, stream>>>(x, xbf, nx);
    pack_wt32<<<32, 256, 0, stream>>>(Wb, Wgk, WT32);
    proj_bg<<<64, 256, 0, stream>>>(xbf, WT32, A_log, dtb, bb, gb);
    bcum_kernel<<<64 * NCH, 64, 0, stream>>>(gb, bcum);

    // build BTall in ONE dispatch: Wq^T | Wk^T | Wv^T | Wg^T
    transpose_all_bf16<<<2560, 256, 0, stream>>>(Wq, Wk, Wv, Wg, BTall);

    // fused q|k|v|gate projection (gate -> Zb; Zb untouched until phase3)
    gemm_proj_fused<<<dim3(40, 32), 256, 0, stream>>>(xbf, BTall, preQ, preK, preV, Zb);

    conv_silu_norm<<<Mrows * HQc, 128, 0, stream>>>(preQ, cq, qcb, HQc, 1, qscale);
    conv_silu_norm<<<Mrows * HKc, 128, 0, stream>>>(preK, ck, kcb, HKc, 1, 1.0f);
    conv_silu_norm<<<Mrows * HKc, 128, 0, stream>>>(preV, cv, vcb, HKc, 0, 1.0f);

    // chunked delta-rule (Z in the dead xbf slot)
    gdn_phase1<<<64 * NCH, 256, 0, stream>>>(kcb, vcb, bb, bcum, Uw, Zdelta);
    gdn_phase2<<<256, 256, 0, stream>>>(qcb, kcb, Uw, Zdelta, bcum, Obuf);
    // phase3 + fused gated RMSNorm: writes normalized bf16 to nrm (Z dead)
    gdn_phase3<<<64 * NCH, 256, 0, stream>>>(qcb, kcb, Uw, bcum, Obuf, Zb, onw, nrm);

    // output projection: d_out fp32 = nrm @ Wo  (Uw dead after phase 3)
    transpose_to_bf16<<<dim3(32, 32), 256, 0, stream>>>(Wo, (__hip_bfloat16*)Uw, 2048, 2048);
    gemm_bt_n64_f32<<<dim3(32, 32), 256, 0, stream>>>(nrm, (__hip_bfloat16*)Uw, (float*)d_out, 2048, 2048);
}